// Round 5
// baseline (422.910 us; speedup 1.0000x reference)
//
#include <hip/hip_runtime.h>

#define N_NODES 50000
#define N_EDGES 800000
#define DIN 256
#define DOUT 64
#define LN_EPS 1e-5f
#define NB 782        // ceil(N_NODES/64) buckets of 64 dsts
#define BCAP 2048     // bucket capacity (mean 1024, sd ~32 -> 32 sigma)

typedef __attribute__((ext_vector_type(8))) short bfrag8;
typedef __attribute__((ext_vector_type(4))) float f32x4;

__device__ inline unsigned short f2bf(float f) {
    unsigned u = __builtin_bit_cast(unsigned, f);
    u += 0x7fffu + ((u >> 16) & 1u);          // round-to-nearest-even
    return (unsigned short)(u >> 16);
}
__device__ inline float bf2f(unsigned short b) {
    unsigned u = ((unsigned)b) << 16;
    return __builtin_bit_cast(float, u);
}

// ---------------- partition: count degrees + bucket edges by dst/64 ----------
// 512 thr x 16 edges = 8192 edges/block. LDS histogram -> one global
// reservation per (block,bucket) -> bucket writes are contiguous runs
// (~10 edges avg) instead of isolated 4B scatters (kills the 16x write amp).
__global__ __launch_bounds__(512) void partition_kernel(
    const int* __restrict__ ei, int* __restrict__ cnt, int* __restrict__ gcur,
    unsigned* __restrict__ bdata) {
    __shared__ int hist[NB];
    __shared__ int hbase[NB];
    __shared__ int lcur[NB];
    const int tid = threadIdx.x;
    for (int c = tid; c < NB; c += 512) { hist[c] = 0; lcur[c] = 0; }
    __syncthreads();
    const int chunk = blockIdx.x * 8192;
    unsigned u[16];
    int bk[16];
    #pragma unroll
    for (int i = 0; i < 16; ++i) {
        int e = chunk + i * 512 + tid;
        if (e < N_EDGES) {
            int s = ei[e];
            int d = ei[N_EDGES + e];
            u[i] = (unsigned)s | ((unsigned)(d & 63) << 17);
            bk[i] = d >> 6;
            atomicAdd(&cnt[d], 1);
            atomicAdd(&hist[bk[i]], 1);
        } else { bk[i] = -1; u[i] = 0; }
    }
    __syncthreads();
    for (int c = tid; c < NB; c += 512) {
        int n = hist[c];
        hbase[c] = n ? atomicAdd(&gcur[c], n) : 0;
    }
    __syncthreads();
    #pragma unroll
    for (int i = 0; i < 16; ++i) {
        if (bk[i] >= 0) {
            int off = hbase[bk[i]] + atomicAdd(&lcur[bk[i]], 1);
            if (off < BCAP) bdata[(size_t)bk[i] * BCAP + off] = u[i];
        }
    }
}

// ---------------- dinv ----------------
__global__ void dinv_kernel(const int* __restrict__ cnt, float* __restrict__ dinv) {
    int i = blockIdx.x * 256 + threadIdx.x;
    if (i < N_NODES) dinv[i] = rsqrtf((float)(cnt[i] + 1));   // +1 self loop
}

// ---------------- MFMA GEMM: h[n][d] = sum_k xs[n][k] * W[d][k], h in bf16 ----
__global__ __launch_bounds__(256) void gemm_kernel(const float* __restrict__ xs,
                                                   const float* __restrict__ W,
                                                   unsigned short* __restrict__ h) {
    __shared__ bfrag8 wg[64 * 32];   // 32KB bf16 W
    const int tid = threadIdx.x;
    #pragma unroll
    for (int i = 0; i < 8; ++i) {
        int gi = tid + i * 256;              // 0..2047
        int d = gi >> 5, g = gi & 31;
        const float* src = W + d * 256 + g * 8;
        f32x4 f0 = *(const f32x4*)src;
        f32x4 f1 = *(const f32x4*)(src + 4);
        union { unsigned short us[8]; bfrag8 v; } p;
        p.us[0] = f2bf(f0.x); p.us[1] = f2bf(f0.y);
        p.us[2] = f2bf(f0.z); p.us[3] = f2bf(f0.w);
        p.us[4] = f2bf(f1.x); p.us[5] = f2bf(f1.y);
        p.us[6] = f2bf(f1.z); p.us[7] = f2bf(f1.w);
        wg[d * 32 + (g ^ (d & 7))] = p.v;
    }
    __syncthreads();

    const int lane = tid & 63, wv = tid >> 6;
    const int n0 = (blockIdx.x * 4 + wv) * 16;
    int arow = n0 + (lane & 15);
    if (arow >= N_NODES) arow = N_NODES - 1;          // clamp (loads only)
    const float* xrow = xs + (size_t)arow * DIN + (lane >> 4) * 8;

    f32x4 acc[4] = {{0.f, 0.f, 0.f, 0.f}, {0.f, 0.f, 0.f, 0.f},
                    {0.f, 0.f, 0.f, 0.f}, {0.f, 0.f, 0.f, 0.f}};
    const int swz = lane & 7;
    #pragma unroll
    for (int s = 0; s < 8; ++s) {
        f32x4 xa = *(const f32x4*)(xrow + s * 32);
        f32x4 xb = *(const f32x4*)(xrow + s * 32 + 4);
        union { unsigned short us[8]; bfrag8 v; } a;
        a.us[0] = f2bf(xa.x); a.us[1] = f2bf(xa.y);
        a.us[2] = f2bf(xa.z); a.us[3] = f2bf(xa.w);
        a.us[4] = f2bf(xb.x); a.us[5] = f2bf(xb.y);
        a.us[6] = f2bf(xb.z); a.us[7] = f2bf(xb.w);
        int g = s * 4 + (lane >> 4);
        #pragma unroll
        for (int t = 0; t < 4; ++t) {
            bfrag8 b = wg[(t * 16 + (lane & 15)) * 32 + (g ^ swz)];
            acc[t] = __builtin_amdgcn_mfma_f32_16x16x32_bf16(a.v, b, acc[t], 0, 0, 0);
        }
    }
    // C/D: col = lane&15, row = (lane>>4)*4 + r
    #pragma unroll
    for (int t = 0; t < 4; ++t) {
        #pragma unroll
        for (int r = 0; r < 4; ++r) {
            int row = n0 + (lane >> 4) * 4 + r;
            if (row < N_NODES)
                h[(size_t)row * DOUT + t * 16 + (lane & 15)] = f2bf(acc[t][r]);
        }
    }
}

// ---------------- bucket aggregate + self loop + bias + LayerNorm ------------
// block = bucket (64 dsts), 512 thr = 8 waves. Wave-per-edge: edge word is a
// wave-uniform broadcast load; h[src] row = one coalesced 128B read; partial
// sums via ds_add_f32 into acc[64][64] fp32 (lane->bank 2-way = free).
__global__ __launch_bounds__(512) void agg_ln_kernel(
    const unsigned* __restrict__ bdata, const int* __restrict__ gcur,
    const unsigned short* __restrict__ h, const float* __restrict__ dinv,
    const float* __restrict__ bias, const float* __restrict__ gamma,
    const float* __restrict__ beta, float* __restrict__ out) {
    __shared__ float acc[64 * 64];   // 16KB
    const int tid = threadIdx.x, lane = tid & 63, wv = tid >> 6;
    const int b = blockIdx.x;
    {
        float4* a4 = (float4*)acc;
        #pragma unroll
        for (int i = 0; i < 2; ++i) a4[tid + i * 512] = make_float4(0.f, 0.f, 0.f, 0.f);
    }
    int cntb = gcur[b];
    if (cntb > BCAP) cntb = BCAP;
    __syncthreads();
    const unsigned* bd = bdata + (size_t)b * BCAP;
    for (int idx = wv; idx < cntb; idx += 8) {
        unsigned u = bd[idx];
        int src = u & 0x1FFFF;
        int dl = u >> 17;
        float w = dinv[src];
        float hv = bf2f(h[(size_t)src * DOUT + lane]);
        atomicAdd(&acc[dl * 64 + lane], hv * w);
    }
    __syncthreads();
    #pragma unroll
    for (int rr = 0; rr < 8; ++rr) {
        int r = wv + rr * 8;
        int node = b * 64 + r;
        if (node < N_NODES) {
            float di = dinv[node];
            float a = acc[r * 64 + lane] + bf2f(h[(size_t)node * DOUT + lane]) * di;
            a = a * di + bias[lane];
            float sum = a;
            #pragma unroll
            for (int d = 1; d < 64; d <<= 1) sum += __shfl_xor(sum, d, 64);
            float mu = sum * (1.0f / 64.0f);
            float diff = a - mu;
            float vs = diff * diff;
            #pragma unroll
            for (int d = 1; d < 64; d <<= 1) vs += __shfl_xor(vs, d, 64);
            float var = vs * (1.0f / 64.0f);
            float rinv = rsqrtf(var + LN_EPS);
            out[(size_t)node * DOUT + lane] = diff * rinv * gamma[lane] + beta[lane];
        }
    }
}

extern "C" void kernel_launch(void* const* d_in, const int* in_sizes, int n_in,
                              void* d_out, int out_size, void* d_ws, size_t ws_size,
                              hipStream_t stream) {
    const float* xs    = (const float*)d_in[0];
    const int*   ei    = (const int*)d_in[1];
    const float* W     = (const float*)d_in[2];
    const float* bias  = (const float*)d_in[3];
    const float* gamma = (const float*)d_in[4];
    const float* beta  = (const float*)d_in[5];
    float* out = (float*)d_out;

    char* base = (char*)d_ws;
    auto align_up = [](size_t x) { return (x + 255) & ~(size_t)255; };
    size_t o = 0;
    int* cnt    = (int*)(base + o);      o = align_up(o + (size_t)N_NODES * 4);
    int* gcur   = (int*)(base + o);      o = align_up(o + (size_t)NB * 4);
    size_t zero_bytes = o;               // cnt + gcur
    float* dinv = (float*)(base + o);    o = align_up(o + (size_t)N_NODES * 4);
    unsigned* bdata = (unsigned*)(base + o);
    o = align_up(o + (size_t)NB * BCAP * 4);
    unsigned short* h = (unsigned short*)(base + o);
    o = align_up(o + (size_t)N_NODES * DOUT * 2);
    (void)ws_size; (void)in_sizes; (void)n_in; (void)out_size;

    hipMemsetAsync(d_ws, 0, zero_bytes, stream);
    partition_kernel<<<(N_EDGES + 8191) / 8192, 512, 0, stream>>>(ei, cnt, gcur, bdata);
    gemm_kernel<<<(N_NODES + 63) / 64, 256, 0, stream>>>(xs, W, h);
    dinv_kernel<<<(N_NODES + 255) / 256, 256, 0, stream>>>(cnt, dinv);
    agg_ln_kernel<<<NB, 512, 0, stream>>>(bdata, gcur, h, dinv, bias, gamma, beta, out);
}

// Round 6
// 399.333 us; speedup vs baseline: 1.0590x; 1.0590x over previous
//
#include <hip/hip_runtime.h>

#define N_NODES 50000
#define N_EDGES 800000
#define DIN 256
#define DOUT 64
#define LN_EPS 1e-5f
#define NB 782        // ceil(N_NODES/64) buckets of 64 dsts
#define BCAP 2048     // bucket capacity (mean 1024, sd ~32 -> 32 sigma)

typedef __attribute__((ext_vector_type(8))) short bfrag8;
typedef __attribute__((ext_vector_type(4))) float f32x4;

__device__ inline unsigned short f2bf(float f) {
    unsigned u = __builtin_bit_cast(unsigned, f);
    u += 0x7fffu + ((u >> 16) & 1u);          // round-to-nearest-even
    return (unsigned short)(u >> 16);
}
__device__ inline float bf2f(unsigned short b) {
    unsigned u = ((unsigned)b) << 16;
    return __builtin_bit_cast(float, u);
}

// ---------------- partition: bucket edges by dst/64 (no global cnt atomics) --
// 512 thr x 16 edges = 8192 edges/block. LDS histogram -> one global
// reservation per (block,bucket) -> bucket writes are contiguous runs.
__global__ __launch_bounds__(512) void partition_kernel(
    const int* __restrict__ ei, int* __restrict__ gcur, unsigned* __restrict__ bdata) {
    __shared__ int hist[NB];
    __shared__ int hbase[NB];
    __shared__ int lcur[NB];
    const int tid = threadIdx.x;
    for (int c = tid; c < NB; c += 512) { hist[c] = 0; lcur[c] = 0; }
    __syncthreads();
    const int chunk = blockIdx.x * 8192;
    unsigned u[16];
    int bk[16];
    #pragma unroll
    for (int i = 0; i < 16; ++i) {
        int e = chunk + i * 512 + tid;
        if (e < N_EDGES) {
            int s = ei[e];
            int d = ei[N_EDGES + e];
            u[i] = (unsigned)s | ((unsigned)(d & 63) << 17);
            bk[i] = d >> 6;
            atomicAdd(&hist[bk[i]], 1);
        } else { bk[i] = -1; u[i] = 0; }
    }
    __syncthreads();
    for (int c = tid; c < NB; c += 512) {
        int n = hist[c];
        hbase[c] = n ? atomicAdd(&gcur[c], n) : 0;
    }
    __syncthreads();
    #pragma unroll
    for (int i = 0; i < 16; ++i) {
        if (bk[i] >= 0) {
            int off = hbase[bk[i]] + atomicAdd(&lcur[bk[i]], 1);
            if (off < BCAP) bdata[(size_t)bk[i] * BCAP + off] = u[i];
        }
    }
}

// ---------------- per-bucket degree hist -> dinv (no atomics to global) ------
__global__ __launch_bounds__(512) void bucket_dinv_kernel(
    const unsigned* __restrict__ bdata, const int* __restrict__ gcur,
    float* __restrict__ dinv) {
    __shared__ int hist[64];
    const int tid = threadIdx.x, b = blockIdx.x;
    if (tid < 64) hist[tid] = 0;
    __syncthreads();
    int cntb = gcur[b];
    if (cntb > BCAP) cntb = BCAP;
    const unsigned* bd = bdata + (size_t)b * BCAP;
    for (int i = tid; i < cntb; i += 512)
        atomicAdd(&hist[bd[i] >> 17], 1);
    __syncthreads();
    int node = b * 64 + tid;
    if (tid < 64 && node < N_NODES)
        dinv[node] = rsqrtf((float)(hist[tid] + 1));   // +1 self loop
}

// ---------------- MFMA GEMM: h[n][d] = sum_k xs[n][k] * W[d][k], h in bf16 ----
__global__ __launch_bounds__(256) void gemm_kernel(const float* __restrict__ xs,
                                                   const float* __restrict__ W,
                                                   unsigned short* __restrict__ h) {
    __shared__ bfrag8 wg[64 * 32];   // 32KB bf16 W
    const int tid = threadIdx.x;
    #pragma unroll
    for (int i = 0; i < 8; ++i) {
        int gi = tid + i * 256;              // 0..2047
        int d = gi >> 5, g = gi & 31;
        const float* src = W + d * 256 + g * 8;
        f32x4 f0 = *(const f32x4*)src;
        f32x4 f1 = *(const f32x4*)(src + 4);
        union { unsigned short us[8]; bfrag8 v; } p;
        p.us[0] = f2bf(f0.x); p.us[1] = f2bf(f0.y);
        p.us[2] = f2bf(f0.z); p.us[3] = f2bf(f0.w);
        p.us[4] = f2bf(f1.x); p.us[5] = f2bf(f1.y);
        p.us[6] = f2bf(f1.z); p.us[7] = f2bf(f1.w);
        wg[d * 32 + (g ^ (d & 7))] = p.v;
    }
    __syncthreads();

    const int lane = tid & 63, wv = tid >> 6;
    const int n0 = (blockIdx.x * 4 + wv) * 16;
    int arow = n0 + (lane & 15);
    if (arow >= N_NODES) arow = N_NODES - 1;          // clamp (loads only)
    const float* xrow = xs + (size_t)arow * DIN + (lane >> 4) * 8;

    f32x4 acc[4] = {{0.f, 0.f, 0.f, 0.f}, {0.f, 0.f, 0.f, 0.f},
                    {0.f, 0.f, 0.f, 0.f}, {0.f, 0.f, 0.f, 0.f}};
    const int swz = lane & 7;
    #pragma unroll
    for (int s = 0; s < 8; ++s) {
        f32x4 xa = *(const f32x4*)(xrow + s * 32);
        f32x4 xb = *(const f32x4*)(xrow + s * 32 + 4);
        union { unsigned short us[8]; bfrag8 v; } a;
        a.us[0] = f2bf(xa.x); a.us[1] = f2bf(xa.y);
        a.us[2] = f2bf(xa.z); a.us[3] = f2bf(xa.w);
        a.us[4] = f2bf(xb.x); a.us[5] = f2bf(xb.y);
        a.us[6] = f2bf(xb.z); a.us[7] = f2bf(xb.w);
        int g = s * 4 + (lane >> 4);
        #pragma unroll
        for (int t = 0; t < 4; ++t) {
            bfrag8 b = wg[(t * 16 + (lane & 15)) * 32 + (g ^ swz)];
            acc[t] = __builtin_amdgcn_mfma_f32_16x16x32_bf16(a.v, b, acc[t], 0, 0, 0);
        }
    }
    // C/D: col = lane&15, row = (lane>>4)*4 + r
    #pragma unroll
    for (int t = 0; t < 4; ++t) {
        #pragma unroll
        for (int r = 0; r < 4; ++r) {
            int row = n0 + (lane >> 4) * 4 + r;
            if (row < N_NODES)
                h[(size_t)row * DOUT + t * 16 + (lane & 15)] = f2bf(acc[t][r]);
        }
    }
}

// ---------------- bucket aggregate + self loop + bias + LayerNorm ------------
// block = bucket (64 dsts), 512 thr = 8 waves, lane = feature.
// 8-wide unrolled edge loop: 8 independent edge-word loads, then 8 independent
// dinv/h-row loads, then 8 LDS float atomics -> 8x MLP on the latency chain.
__global__ __launch_bounds__(512) void agg_ln_kernel(
    const unsigned* __restrict__ bdata, const int* __restrict__ gcur,
    const unsigned short* __restrict__ h, const float* __restrict__ dinv,
    const float* __restrict__ bias, const float* __restrict__ gamma,
    const float* __restrict__ beta, float* __restrict__ out) {
    __shared__ float acc[64 * 64];   // 16KB
    const int tid = threadIdx.x, lane = tid & 63, wv = tid >> 6;
    const int b = blockIdx.x;
    {
        float4* a4 = (float4*)acc;
        #pragma unroll
        for (int i = 0; i < 2; ++i) a4[tid + i * 512] = make_float4(0.f, 0.f, 0.f, 0.f);
    }
    int cntb = gcur[b];
    if (cntb > BCAP) cntb = BCAP;
    __syncthreads();
    const unsigned* bd = bdata + (size_t)b * BCAP;
    for (int base = wv * 8; base < cntb; base += 64) {
        unsigned u[8];
        #pragma unroll
        for (int i = 0; i < 8; ++i)
            u[i] = (base + i < cntb) ? bd[base + i] : 0xFFFFFFFFu;
        float w[8], hv[8];
        #pragma unroll
        for (int i = 0; i < 8; ++i) {
            if (u[i] != 0xFFFFFFFFu) {
                int src = u[i] & 0x1FFFF;
                w[i] = dinv[src];
                hv[i] = bf2f(h[(size_t)src * DOUT + lane]);
            }
        }
        #pragma unroll
        for (int i = 0; i < 8; ++i) {
            if (u[i] != 0xFFFFFFFFu)
                atomicAdd(&acc[(int)(u[i] >> 17) * 64 + lane], hv[i] * w[i]);
        }
    }
    __syncthreads();
    #pragma unroll
    for (int rr = 0; rr < 8; ++rr) {
        int r = wv + rr * 8;
        int node = b * 64 + r;
        if (node < N_NODES) {
            float di = dinv[node];
            float a = acc[r * 64 + lane] + bf2f(h[(size_t)node * DOUT + lane]) * di;
            a = a * di + bias[lane];
            float sum = a;
            #pragma unroll
            for (int d = 1; d < 64; d <<= 1) sum += __shfl_xor(sum, d, 64);
            float mu = sum * (1.0f / 64.0f);
            float diff = a - mu;
            float vs = diff * diff;
            #pragma unroll
            for (int d = 1; d < 64; d <<= 1) vs += __shfl_xor(vs, d, 64);
            float var = vs * (1.0f / 64.0f);
            float rinv = rsqrtf(var + LN_EPS);
            out[(size_t)node * DOUT + lane] = diff * rinv * gamma[lane] + beta[lane];
        }
    }
}

extern "C" void kernel_launch(void* const* d_in, const int* in_sizes, int n_in,
                              void* d_out, int out_size, void* d_ws, size_t ws_size,
                              hipStream_t stream) {
    const float* xs    = (const float*)d_in[0];
    const int*   ei    = (const int*)d_in[1];
    const float* W     = (const float*)d_in[2];
    const float* bias  = (const float*)d_in[3];
    const float* gamma = (const float*)d_in[4];
    const float* beta  = (const float*)d_in[5];
    float* out = (float*)d_out;

    char* base = (char*)d_ws;
    auto align_up = [](size_t x) { return (x + 255) & ~(size_t)255; };
    size_t o = 0;
    int* gcur   = (int*)(base + o);      o = align_up(o + (size_t)NB * 4);
    size_t zero_bytes = o;               // gcur only
    float* dinv = (float*)(base + o);    o = align_up(o + (size_t)N_NODES * 4);
    unsigned* bdata = (unsigned*)(base + o);
    o = align_up(o + (size_t)NB * BCAP * 4);
    unsigned short* h = (unsigned short*)(base + o);
    o = align_up(o + (size_t)N_NODES * DOUT * 2);
    (void)ws_size; (void)in_sizes; (void)n_in; (void)out_size;

    hipMemsetAsync(d_ws, 0, zero_bytes, stream);
    partition_kernel<<<(N_EDGES + 8191) / 8192, 512, 0, stream>>>(ei, gcur, bdata);
    gemm_kernel<<<(N_NODES + 63) / 64, 256, 0, stream>>>(xs, W, h);
    bucket_dinv_kernel<<<NB, 512, 0, stream>>>(bdata, gcur, dinv);
    agg_ln_kernel<<<NB, 512, 0, stream>>>(bdata, gcur, h, dinv, bias, gamma, beta, out);
}

// Round 7
// 396.566 us; speedup vs baseline: 1.0664x; 1.0070x over previous
//
#include <hip/hip_runtime.h>

#define N_NODES 50000
#define N_EDGES 800000
#define DIN 256
#define DOUT 64
#define LN_EPS 1e-5f
#define NB 782        // ceil(N_NODES/64) buckets of 64 dsts
#define BCAP 2048     // bucket capacity (mean 1024, sd ~32)

typedef __attribute__((ext_vector_type(8))) short bfrag8;
typedef __attribute__((ext_vector_type(4))) float f32x4;

__device__ inline unsigned short f2bf(float f) {
    unsigned u = __builtin_bit_cast(unsigned, f);
    u += 0x7fffu + ((u >> 16) & 1u);          // round-to-nearest-even
    return (unsigned short)(u >> 16);
}
__device__ inline float bf2f(unsigned short b) {
    unsigned u = ((unsigned)b) << 16;
    return __builtin_bit_cast(float, u);
}

// ---------------- partition: bucket edges by dst/64 ----------------
__global__ __launch_bounds__(512) void partition_kernel(
    const int* __restrict__ ei, int* __restrict__ gcur, unsigned* __restrict__ bdata) {
    __shared__ int hist[NB];
    __shared__ int hbase[NB];
    __shared__ int lcur[NB];
    const int tid = threadIdx.x;
    for (int c = tid; c < NB; c += 512) { hist[c] = 0; lcur[c] = 0; }
    __syncthreads();
    const int chunk = blockIdx.x * 8192;
    unsigned u[16];
    int bk[16];
    #pragma unroll
    for (int i = 0; i < 16; ++i) {
        int e = chunk + i * 512 + tid;
        if (e < N_EDGES) {
            int s = ei[e];
            int d = ei[N_EDGES + e];
            u[i] = (unsigned)s | ((unsigned)(d & 63) << 17);
            bk[i] = d >> 6;
            atomicAdd(&hist[bk[i]], 1);
        } else { bk[i] = -1; u[i] = 0; }
    }
    __syncthreads();
    for (int c = tid; c < NB; c += 512) {
        int n = hist[c];
        hbase[c] = n ? atomicAdd(&gcur[c], n) : 0;
    }
    __syncthreads();
    #pragma unroll
    for (int i = 0; i < 16; ++i) {
        if (bk[i] >= 0) {
            int off = hbase[bk[i]] + atomicAdd(&lcur[bk[i]], 1);
            if (off < BCAP) bdata[(size_t)bk[i] * BCAP + off] = u[i];
        }
    }
}

// ---------------- per-bucket degree hist -> dinv ----------------
__global__ __launch_bounds__(512) void bucket_dinv_kernel(
    const unsigned* __restrict__ bdata, const int* __restrict__ gcur,
    float* __restrict__ dinv) {
    __shared__ int hist[64];
    const int tid = threadIdx.x, b = blockIdx.x;
    if (tid < 64) hist[tid] = 0;
    __syncthreads();
    int cntb = gcur[b];
    if (cntb > BCAP) cntb = BCAP;
    const unsigned* bd = bdata + (size_t)b * BCAP;
    for (int i = tid; i < cntb; i += 512)
        atomicAdd(&hist[bd[i] >> 17], 1);
    __syncthreads();
    int node = b * 64 + tid;
    if (tid < 64 && node < N_NODES)
        dinv[node] = rsqrtf((float)(hist[tid] + 1));   // +1 self loop
}

// ------- MFMA GEMM: hs[n][d] = (sum_k xs[n][k] * W[d][k]) * dinv[n], bf16 ----
__global__ __launch_bounds__(256) void gemm_kernel(const float* __restrict__ xs,
                                                   const float* __restrict__ W,
                                                   const float* __restrict__ dinv,
                                                   unsigned short* __restrict__ hs) {
    __shared__ bfrag8 wg[64 * 32];   // 32KB bf16 W
    const int tid = threadIdx.x;
    #pragma unroll
    for (int i = 0; i < 8; ++i) {
        int gi = tid + i * 256;              // 0..2047
        int d = gi >> 5, g = gi & 31;
        const float* src = W + d * 256 + g * 8;
        f32x4 f0 = *(const f32x4*)src;
        f32x4 f1 = *(const f32x4*)(src + 4);
        union { unsigned short us[8]; bfrag8 v; } p;
        p.us[0] = f2bf(f0.x); p.us[1] = f2bf(f0.y);
        p.us[2] = f2bf(f0.z); p.us[3] = f2bf(f0.w);
        p.us[4] = f2bf(f1.x); p.us[5] = f2bf(f1.y);
        p.us[6] = f2bf(f1.z); p.us[7] = f2bf(f1.w);
        wg[d * 32 + (g ^ (d & 7))] = p.v;
    }
    __syncthreads();

    const int lane = tid & 63, wv = tid >> 6;
    const int n0 = (blockIdx.x * 4 + wv) * 16;
    int arow = n0 + (lane & 15);
    if (arow >= N_NODES) arow = N_NODES - 1;          // clamp (loads only)
    const float* xrow = xs + (size_t)arow * DIN + (lane >> 4) * 8;

    f32x4 acc[4] = {{0.f, 0.f, 0.f, 0.f}, {0.f, 0.f, 0.f, 0.f},
                    {0.f, 0.f, 0.f, 0.f}, {0.f, 0.f, 0.f, 0.f}};
    const int swz = lane & 7;
    #pragma unroll
    for (int s = 0; s < 8; ++s) {
        f32x4 xa = *(const f32x4*)(xrow + s * 32);
        f32x4 xb = *(const f32x4*)(xrow + s * 32 + 4);
        union { unsigned short us[8]; bfrag8 v; } a;
        a.us[0] = f2bf(xa.x); a.us[1] = f2bf(xa.y);
        a.us[2] = f2bf(xa.z); a.us[3] = f2bf(xa.w);
        a.us[4] = f2bf(xb.x); a.us[5] = f2bf(xb.y);
        a.us[6] = f2bf(xb.z); a.us[7] = f2bf(xb.w);
        int g = s * 4 + (lane >> 4);
        #pragma unroll
        for (int t = 0; t < 4; ++t) {
            bfrag8 b = wg[(t * 16 + (lane & 15)) * 32 + (g ^ swz)];
            acc[t] = __builtin_amdgcn_mfma_f32_16x16x32_bf16(a.v, b, acc[t], 0, 0, 0);
        }
    }
    // C/D: col = lane&15, row = (lane>>4)*4 + r ; scale by dinv[row] on store
    #pragma unroll
    for (int t = 0; t < 4; ++t) {
        #pragma unroll
        for (int r = 0; r < 4; ++r) {
            int row = n0 + (lane >> 4) * 4 + r;
            if (row < N_NODES) {
                float dr = dinv[row];
                hs[(size_t)row * DOUT + t * 16 + (lane & 15)] = f2bf(acc[t][r] * dr);
            }
        }
    }
}

// ---------------- bucket aggregate + self loop + bias + LayerNorm ------------
// block = bucket (64 dsts), 512 thr = 8 waves, lane = feature.
// Each wave owns a contiguous 16-aligned span; full groups of 16 edges are
// UNCONDITIONAL: 4x uint4 edge-word loads -> 16 independent hs-row loads ->
// 16 ds_add. No branches between loads => real MLP (watch VGPR jump).
__global__ __launch_bounds__(512) void agg_ln_kernel(
    const unsigned* __restrict__ bdata, const int* __restrict__ gcur,
    const unsigned short* __restrict__ hs, const float* __restrict__ dinv,
    const float* __restrict__ bias, const float* __restrict__ gamma,
    const float* __restrict__ beta, float* __restrict__ out) {
    __shared__ float acc[64 * 64];   // 16KB
    const int tid = threadIdx.x, lane = tid & 63, wv = tid >> 6;
    const int b = blockIdx.x;
    {
        float4* a4 = (float4*)acc;
        a4[tid] = make_float4(0.f, 0.f, 0.f, 0.f);
        a4[tid + 512] = make_float4(0.f, 0.f, 0.f, 0.f);
    }
    int cntb = gcur[b];
    if (cntb > BCAP) cntb = BCAP;
    __syncthreads();
    const unsigned* bd = bdata + (size_t)b * BCAP;
    int span = (((cntb + 7) >> 3) + 15) & ~15;     // per-wave, 16-aligned
    int i = wv * span;
    int i1 = i + span; if (i1 > cntb) i1 = cntb;
    for (; i + 16 <= i1; i += 16) {
        uint4 ua = *(const uint4*)(bd + i);
        uint4 ub = *(const uint4*)(bd + i + 4);
        uint4 uc = *(const uint4*)(bd + i + 8);
        uint4 ud = *(const uint4*)(bd + i + 12);
        unsigned s[16] = {ua.x, ua.y, ua.z, ua.w, ub.x, ub.y, ub.z, ub.w,
                          uc.x, uc.y, uc.z, uc.w, ud.x, ud.y, ud.z, ud.w};
        float hv[16];
        #pragma unroll
        for (int j = 0; j < 16; ++j)
            hv[j] = bf2f(hs[(size_t)(s[j] & 0x1FFFF) * DOUT + lane]);
        #pragma unroll
        for (int j = 0; j < 16; ++j)
            atomicAdd(&acc[(int)(s[j] >> 17) * 64 + lane], hv[j]);
    }
    for (; i < i1; ++i) {
        unsigned u = bd[i];
        atomicAdd(&acc[(int)(u >> 17) * 64 + lane],
                  bf2f(hs[(size_t)(u & 0x1FFFF) * DOUT + lane]));
    }
    __syncthreads();
    #pragma unroll
    for (int rr = 0; rr < 8; ++rr) {
        int r = wv + rr * 8;
        int node = b * 64 + r;
        if (node < N_NODES) {
            float di = dinv[node];
            float a = (acc[r * 64 + lane] + bf2f(hs[(size_t)node * DOUT + lane])) * di
                      + bias[lane];
            float sum = a;
            #pragma unroll
            for (int d = 1; d < 64; d <<= 1) sum += __shfl_xor(sum, d, 64);
            float mu = sum * (1.0f / 64.0f);
            float diff = a - mu;
            float vs = diff * diff;
            #pragma unroll
            for (int d = 1; d < 64; d <<= 1) vs += __shfl_xor(vs, d, 64);
            float var = vs * (1.0f / 64.0f);
            float rinv = rsqrtf(var + LN_EPS);
            out[(size_t)node * DOUT + lane] = diff * rinv * gamma[lane] + beta[lane];
        }
    }
}

extern "C" void kernel_launch(void* const* d_in, const int* in_sizes, int n_in,
                              void* d_out, int out_size, void* d_ws, size_t ws_size,
                              hipStream_t stream) {
    const float* xs    = (const float*)d_in[0];
    const int*   ei    = (const int*)d_in[1];
    const float* W     = (const float*)d_in[2];
    const float* bias  = (const float*)d_in[3];
    const float* gamma = (const float*)d_in[4];
    const float* beta  = (const float*)d_in[5];
    float* out = (float*)d_out;

    char* base = (char*)d_ws;
    auto align_up = [](size_t x) { return (x + 255) & ~(size_t)255; };
    size_t o = 0;
    int* gcur   = (int*)(base + o);      o = align_up(o + (size_t)NB * 4);
    size_t zero_bytes = o;               // gcur only
    float* dinv = (float*)(base + o);    o = align_up(o + (size_t)N_NODES * 4);
    unsigned* bdata = (unsigned*)(base + o);
    o = align_up(o + (size_t)NB * BCAP * 4);
    unsigned short* hs = (unsigned short*)(base + o);
    o = align_up(o + (size_t)N_NODES * DOUT * 2);
    (void)ws_size; (void)in_sizes; (void)n_in; (void)out_size;

    hipMemsetAsync(d_ws, 0, zero_bytes, stream);
    partition_kernel<<<(N_EDGES + 8191) / 8192, 512, 0, stream>>>(ei, gcur, bdata);
    bucket_dinv_kernel<<<NB, 512, 0, stream>>>(bdata, gcur, dinv);
    gemm_kernel<<<(N_NODES + 63) / 64, 256, 0, stream>>>(xs, W, dinv, hs);
    agg_ln_kernel<<<NB, 512, 0, stream>>>(bdata, gcur, hs, dinv, bias, gamma, beta, out);
}

// Round 8
// 395.887 us; speedup vs baseline: 1.0683x; 1.0017x over previous
//
#include <hip/hip_runtime.h>

#define N_NODES 50000
#define N_EDGES 800000
#define DIN 256
#define DOUT 64
#define LN_EPS 1e-5f
#define NB 782        // ceil(N_NODES/64) buckets of 64 dsts
#define BCAP 2048     // bucket capacity (mean 1024, sd ~32)

typedef __attribute__((ext_vector_type(8))) short bfrag8;
typedef __attribute__((ext_vector_type(4))) float f32x4;

__device__ inline unsigned short f2bf(float f) {
    unsigned u = __builtin_bit_cast(unsigned, f);
    u += 0x7fffu + ((u >> 16) & 1u);          // round-to-nearest-even
    return (unsigned short)(u >> 16);
}
__device__ inline float bf2f(unsigned short b) {
    unsigned u = ((unsigned)b) << 16;
    return __builtin_bit_cast(float, u);
}

// ---------------- partition: bucket edges by dst/64 ----------------
__global__ __launch_bounds__(512) void partition_kernel(
    const int* __restrict__ ei, int* __restrict__ gcur, unsigned* __restrict__ bdata) {
    __shared__ int hist[NB];
    __shared__ int hbase[NB];
    __shared__ int lcur[NB];
    const int tid = threadIdx.x;
    for (int c = tid; c < NB; c += 512) { hist[c] = 0; lcur[c] = 0; }
    __syncthreads();
    const int chunk = blockIdx.x * 8192;
    unsigned u[16];
    int bk[16];
    #pragma unroll
    for (int i = 0; i < 16; ++i) {
        int e = chunk + i * 512 + tid;
        if (e < N_EDGES) {
            int s = ei[e];
            int d = ei[N_EDGES + e];
            u[i] = (unsigned)s | ((unsigned)(d & 63) << 17);
            bk[i] = d >> 6;
            atomicAdd(&hist[bk[i]], 1);
        } else { bk[i] = -1; u[i] = 0; }
    }
    __syncthreads();
    for (int c = tid; c < NB; c += 512) {
        int n = hist[c];
        hbase[c] = n ? atomicAdd(&gcur[c], n) : 0;
    }
    __syncthreads();
    #pragma unroll
    for (int i = 0; i < 16; ++i) {
        if (bk[i] >= 0) {
            int off = hbase[bk[i]] + atomicAdd(&lcur[bk[i]], 1);
            if (off < BCAP) bdata[(size_t)bk[i] * BCAP + off] = u[i];
        }
    }
}

// ---------------- per-bucket degree hist -> dinv ----------------
__global__ __launch_bounds__(512) void bucket_dinv_kernel(
    const unsigned* __restrict__ bdata, const int* __restrict__ gcur,
    float* __restrict__ dinv) {
    __shared__ int hist[64];
    const int tid = threadIdx.x, b = blockIdx.x;
    if (tid < 64) hist[tid] = 0;
    __syncthreads();
    int cntb = gcur[b];
    if (cntb > BCAP) cntb = BCAP;
    const unsigned* bd = bdata + (size_t)b * BCAP;
    for (int i = tid; i < cntb; i += 512)
        atomicAdd(&hist[bd[i] >> 17], 1);
    __syncthreads();
    int node = b * 64 + tid;
    if (tid < 64 && node < N_NODES)
        dinv[node] = rsqrtf((float)(hist[tid] + 1));   // +1 self loop
}

// ------- MFMA GEMM: hs[n][d] = (sum_k xs[n][k] * W[d][k]) * dinv[n], bf16 ----
__global__ __launch_bounds__(256) void gemm_kernel(const float* __restrict__ xs,
                                                   const float* __restrict__ W,
                                                   const float* __restrict__ dinv,
                                                   unsigned short* __restrict__ hs) {
    __shared__ bfrag8 wg[64 * 32];   // 32KB bf16 W
    const int tid = threadIdx.x;
    #pragma unroll
    for (int i = 0; i < 8; ++i) {
        int gi = tid + i * 256;              // 0..2047
        int d = gi >> 5, g = gi & 31;
        const float* src = W + d * 256 + g * 8;
        f32x4 f0 = *(const f32x4*)src;
        f32x4 f1 = *(const f32x4*)(src + 4);
        union { unsigned short us[8]; bfrag8 v; } p;
        p.us[0] = f2bf(f0.x); p.us[1] = f2bf(f0.y);
        p.us[2] = f2bf(f0.z); p.us[3] = f2bf(f0.w);
        p.us[4] = f2bf(f1.x); p.us[5] = f2bf(f1.y);
        p.us[6] = f2bf(f1.z); p.us[7] = f2bf(f1.w);
        wg[d * 32 + (g ^ (d & 7))] = p.v;
    }
    __syncthreads();

    const int lane = tid & 63, wv = tid >> 6;
    const int n0 = (blockIdx.x * 4 + wv) * 16;
    int arow = n0 + (lane & 15);
    if (arow >= N_NODES) arow = N_NODES - 1;          // clamp (loads only)
    const float* xrow = xs + (size_t)arow * DIN + (lane >> 4) * 8;

    f32x4 acc[4] = {{0.f, 0.f, 0.f, 0.f}, {0.f, 0.f, 0.f, 0.f},
                    {0.f, 0.f, 0.f, 0.f}, {0.f, 0.f, 0.f, 0.f}};
    const int swz = lane & 7;
    #pragma unroll
    for (int s = 0; s < 8; ++s) {
        f32x4 xa = *(const f32x4*)(xrow + s * 32);
        f32x4 xb = *(const f32x4*)(xrow + s * 32 + 4);
        union { unsigned short us[8]; bfrag8 v; } a;
        a.us[0] = f2bf(xa.x); a.us[1] = f2bf(xa.y);
        a.us[2] = f2bf(xa.z); a.us[3] = f2bf(xa.w);
        a.us[4] = f2bf(xb.x); a.us[5] = f2bf(xb.y);
        a.us[6] = f2bf(xb.z); a.us[7] = f2bf(xb.w);
        int g = s * 4 + (lane >> 4);
        #pragma unroll
        for (int t = 0; t < 4; ++t) {
            bfrag8 b = wg[(t * 16 + (lane & 15)) * 32 + (g ^ swz)];
            acc[t] = __builtin_amdgcn_mfma_f32_16x16x32_bf16(a.v, b, acc[t], 0, 0, 0);
        }
    }
    // C/D: col = lane&15, row = (lane>>4)*4 + r ; scale by dinv[row] on store
    #pragma unroll
    for (int t = 0; t < 4; ++t) {
        #pragma unroll
        for (int r = 0; r < 4; ++r) {
            int row = n0 + (lane >> 4) * 4 + r;
            if (row < N_NODES) {
                float dr = dinv[row];
                hs[(size_t)row * DOUT + t * 16 + (lane & 15)] = f2bf(acc[t][r] * dr);
            }
        }
    }
}

// ---------------- bucket aggregate + self loop + bias + LayerNorm ------------
// block = bucket (64 dsts), 512 thr = 8 waves.
// Per 16-edge group: lane (e=lane>>2, q=lane&3) loads 16B+16B of edge e's hs
// row -> each gather INSTRUCTION carries 32 independent line fetches (MLP the
// scheduler cannot serialize away). LDS acc is rotation-swizzled:
// (dl, f) lives at dl*64 + ((f+dl)&63), so per-instruction banks are spread
// by the random dl (~2-way = free) while register indices stay static.
__global__ __launch_bounds__(512) void agg_ln_kernel(
    const unsigned* __restrict__ bdata, const int* __restrict__ gcur,
    const unsigned short* __restrict__ hs, const float* __restrict__ dinv,
    const float* __restrict__ bias, const float* __restrict__ gamma,
    const float* __restrict__ beta, float* __restrict__ out) {
    __shared__ float acc[64 * 64];   // 16KB
    const int tid = threadIdx.x, lane = tid & 63, wv = tid >> 6;
    const int b = blockIdx.x;
    {
        float4* a4 = (float4*)acc;
        a4[tid] = make_float4(0.f, 0.f, 0.f, 0.f);
        a4[tid + 512] = make_float4(0.f, 0.f, 0.f, 0.f);
    }
    int cntb = gcur[b];
    if (cntb > BCAP) cntb = BCAP;
    __syncthreads();
    const unsigned* bd = bdata + (size_t)b * BCAP;
    int span = (((cntb + 7) >> 3) + 15) & ~15;     // per-wave, 16-aligned
    int i = wv * span;
    int i1 = i + span; if (i1 > cntb) i1 = cntb;

    const int e = lane >> 2;          // edge slot 0..15
    const int q = lane & 3;           // feature quarter 0..3
    const int basef = q * 16;
    for (; i + 16 <= i1; i += 16) {
        unsigned u = bd[i + e];                       // 4 lanes share one word
        int src = (int)(u & 0x1FFFF);
        int dl  = (int)(u >> 17);
        const uint4* rp = (const uint4*)(hs + (size_t)src * DOUT + basef);
        uint4 ra = rp[0];                             // features basef+0..7
        uint4 rb = rp[1];                             // features basef+8..15
        unsigned rw[8] = {ra.x, ra.y, ra.z, ra.w, rb.x, rb.y, rb.z, rb.w};
        float* arow = acc + dl * 64;
        #pragma unroll
        for (int j = 0; j < 8; ++j) {
            float lo = bf2f((unsigned short)(rw[j] & 0xFFFFu));
            float hi = bf2f((unsigned short)(rw[j] >> 16));
            atomicAdd(&arow[(basef + 2 * j + dl) & 63], lo);
            atomicAdd(&arow[(basef + 2 * j + 1 + dl) & 63], hi);
        }
    }
    // tail (<16 edges): wave-uniform per edge, lane = feature
    for (; i < i1; ++i) {
        unsigned u = bd[i];
        int src = (int)(u & 0x1FFFF);
        int dl  = (int)(u >> 17);
        float hv = bf2f(hs[(size_t)src * DOUT + lane]);
        atomicAdd(&acc[dl * 64 + ((lane + dl) & 63)], hv);
    }
    __syncthreads();
    #pragma unroll
    for (int rr = 0; rr < 8; ++rr) {
        int r = wv + rr * 8;
        int node = b * 64 + r;
        if (node < N_NODES) {
            float di = dinv[node];
            float a = (acc[r * 64 + ((lane + r) & 63)]
                       + bf2f(hs[(size_t)node * DOUT + lane])) * di + bias[lane];
            float sum = a;
            #pragma unroll
            for (int d = 1; d < 64; d <<= 1) sum += __shfl_xor(sum, d, 64);
            float mu = sum * (1.0f / 64.0f);
            float diff = a - mu;
            float vs = diff * diff;
            #pragma unroll
            for (int d = 1; d < 64; d <<= 1) vs += __shfl_xor(vs, d, 64);
            float var = vs * (1.0f / 64.0f);
            float rinv = rsqrtf(var + LN_EPS);
            out[(size_t)node * DOUT + lane] = diff * rinv * gamma[lane] + beta[lane];
        }
    }
}

extern "C" void kernel_launch(void* const* d_in, const int* in_sizes, int n_in,
                              void* d_out, int out_size, void* d_ws, size_t ws_size,
                              hipStream_t stream) {
    const float* xs    = (const float*)d_in[0];
    const int*   ei    = (const int*)d_in[1];
    const float* W     = (const float*)d_in[2];
    const float* bias  = (const float*)d_in[3];
    const float* gamma = (const float*)d_in[4];
    const float* beta  = (const float*)d_in[5];
    float* out = (float*)d_out;

    char* base = (char*)d_ws;
    auto align_up = [](size_t x) { return (x + 255) & ~(size_t)255; };
    size_t o = 0;
    int* gcur   = (int*)(base + o);      o = align_up(o + (size_t)NB * 4);
    size_t zero_bytes = o;               // gcur only
    float* dinv = (float*)(base + o);    o = align_up(o + (size_t)N_NODES * 4);
    unsigned* bdata = (unsigned*)(base + o);
    o = align_up(o + (size_t)NB * BCAP * 4);
    unsigned short* hs = (unsigned short*)(base + o);
    o = align_up(o + (size_t)N_NODES * DOUT * 2);
    (void)ws_size; (void)in_sizes; (void)n_in; (void)out_size;

    hipMemsetAsync(d_ws, 0, zero_bytes, stream);
    partition_kernel<<<(N_EDGES + 8191) / 8192, 512, 0, stream>>>(ei, gcur, bdata);
    bucket_dinv_kernel<<<NB, 512, 0, stream>>>(bdata, gcur, dinv);
    gemm_kernel<<<(N_NODES + 63) / 64, 256, 0, stream>>>(xs, W, dinv, hs);
    agg_ln_kernel<<<NB, 512, 0, stream>>>(bdata, gcur, hs, dinv, bias, gamma, beta, out);
}

// Round 9
// 81.981 us; speedup vs baseline: 5.1587x; 4.8290x over previous
//
#include <hip/hip_runtime.h>

#define N_NODES 50000
#define N_EDGES 800000
#define DIN 256
#define DOUT 64
#define LN_EPS 1e-5f
#define NB 782        // ceil(N_NODES/64) buckets of 64 dsts
#define BCAP 2048     // bucket capacity (mean 1024, sd ~32)

typedef __attribute__((ext_vector_type(8))) short bfrag8;
typedef __attribute__((ext_vector_type(4))) float f32x4;

__device__ inline unsigned short f2bf(float f) {
    unsigned u = __builtin_bit_cast(unsigned, f);
    u += 0x7fffu + ((u >> 16) & 1u);          // round-to-nearest-even
    return (unsigned short)(u >> 16);
}
__device__ inline float bf2f(unsigned short b) {
    unsigned u = ((unsigned)b) << 16;
    return __builtin_bit_cast(float, u);
}

// ---------------- partition: bucket edges by dst/64 (coarse radix pass) ------
__global__ __launch_bounds__(512) void partition_kernel(
    const int* __restrict__ ei, int* __restrict__ gcur, unsigned* __restrict__ bdata) {
    __shared__ int hist[NB];
    __shared__ int hbase[NB];
    __shared__ int lcur[NB];
    const int tid = threadIdx.x;
    for (int c = tid; c < NB; c += 512) { hist[c] = 0; lcur[c] = 0; }
    __syncthreads();
    const int chunk = blockIdx.x * 8192;
    unsigned u[16];
    int bk[16];
    #pragma unroll
    for (int i = 0; i < 16; ++i) {
        int e = chunk + i * 512 + tid;
        if (e < N_EDGES) {
            int s = ei[e];
            int d = ei[N_EDGES + e];
            u[i] = (unsigned)s | ((unsigned)(d & 63) << 17);
            bk[i] = d >> 6;
            atomicAdd(&hist[bk[i]], 1);
        } else { bk[i] = -1; u[i] = 0; }
    }
    __syncthreads();
    for (int c = tid; c < NB; c += 512) {
        int n = hist[c];
        hbase[c] = n ? atomicAdd(&gcur[c], n) : 0;
    }
    __syncthreads();
    #pragma unroll
    for (int i = 0; i < 16; ++i) {
        if (bk[i] >= 0) {
            int off = hbase[bk[i]] + atomicAdd(&lcur[bk[i]], 1);
            if (off < BCAP) bdata[(size_t)bk[i] * BCAP + off] = u[i];
        }
    }
}

// ------ per-bucket counting sort by dst + dinv + per-node CSR bounds ---------
// Stage bucket in LDS, hist[64] + wave-0 prefix scan, scatter back IN PLACE
// sorted by local dst. Only 1 LDS atomic per edge (not per edge*feature).
__global__ __launch_bounds__(512) void sort_dinv_kernel(
    unsigned* __restrict__ bdata, const int* __restrict__ gcur,
    float* __restrict__ dinv, int* __restrict__ nstart, int* __restrict__ nend) {
    __shared__ unsigned buf[BCAP];   // 8KB
    __shared__ int hist[64];
    __shared__ int pre[64];
    __shared__ int cur[64];
    const int tid = threadIdx.x, b = blockIdx.x;
    if (tid < 64) { hist[tid] = 0; cur[tid] = 0; }
    __syncthreads();
    int cntb = gcur[b];
    if (cntb > BCAP) cntb = BCAP;
    unsigned* bd = bdata + (size_t)b * BCAP;
    for (int i = tid; i < cntb; i += 512) {
        unsigned u = bd[i];
        buf[i] = u;
        atomicAdd(&hist[u >> 17], 1);
    }
    __syncthreads();
    if (tid < 64) {                      // wave 0: exclusive scan of hist
        int v = hist[tid], s = v;
        #pragma unroll
        for (int d = 1; d < 64; d <<= 1) {
            int t = __shfl_up(s, d, 64);
            if (tid >= d) s += t;
        }
        pre[tid] = s - v;
        int node = b * 64 + tid;
        if (node < N_NODES) {
            dinv[node] = rsqrtf((float)(v + 1));   // +1 self loop
            nstart[node] = b * BCAP + (s - v);
            nend[node]   = b * BCAP + s;
        }
    }
    __syncthreads();
    for (int i = tid; i < cntb; i += 512) {
        unsigned u = buf[i];
        int dl = (int)(u >> 17);
        int off = atomicAdd(&cur[dl], 1);
        bd[pre[dl] + off] = u & 0x1FFFF;           // store src only
    }
}

// ------- MFMA GEMM: hs[n][d] = (sum_k xs[n][k] * W[d][k]) * dinv[n], bf16 ----
__global__ __launch_bounds__(256) void gemm_kernel(const float* __restrict__ xs,
                                                   const float* __restrict__ W,
                                                   const float* __restrict__ dinv,
                                                   unsigned short* __restrict__ hs) {
    __shared__ bfrag8 wg[64 * 32];   // 32KB bf16 W
    const int tid = threadIdx.x;
    #pragma unroll
    for (int i = 0; i < 8; ++i) {
        int gi = tid + i * 256;              // 0..2047
        int d = gi >> 5, g = gi & 31;
        const float* src = W + d * 256 + g * 8;
        f32x4 f0 = *(const f32x4*)src;
        f32x4 f1 = *(const f32x4*)(src + 4);
        union { unsigned short us[8]; bfrag8 v; } p;
        p.us[0] = f2bf(f0.x); p.us[1] = f2bf(f0.y);
        p.us[2] = f2bf(f0.z); p.us[3] = f2bf(f0.w);
        p.us[4] = f2bf(f1.x); p.us[5] = f2bf(f1.y);
        p.us[6] = f2bf(f1.z); p.us[7] = f2bf(f1.w);
        wg[d * 32 + (g ^ (d & 7))] = p.v;
    }
    __syncthreads();

    const int lane = tid & 63, wv = tid >> 6;
    const int n0 = (blockIdx.x * 4 + wv) * 16;
    int arow = n0 + (lane & 15);
    if (arow >= N_NODES) arow = N_NODES - 1;          // clamp (loads only)
    const float* xrow = xs + (size_t)arow * DIN + (lane >> 4) * 8;

    f32x4 acc[4] = {{0.f, 0.f, 0.f, 0.f}, {0.f, 0.f, 0.f, 0.f},
                    {0.f, 0.f, 0.f, 0.f}, {0.f, 0.f, 0.f, 0.f}};
    const int swz = lane & 7;
    #pragma unroll
    for (int s = 0; s < 8; ++s) {
        f32x4 xa = *(const f32x4*)(xrow + s * 32);
        f32x4 xb = *(const f32x4*)(xrow + s * 32 + 4);
        union { unsigned short us[8]; bfrag8 v; } a;
        a.us[0] = f2bf(xa.x); a.us[1] = f2bf(xa.y);
        a.us[2] = f2bf(xa.z); a.us[3] = f2bf(xa.w);
        a.us[4] = f2bf(xb.x); a.us[5] = f2bf(xb.y);
        a.us[6] = f2bf(xb.z); a.us[7] = f2bf(xb.w);
        int g = s * 4 + (lane >> 4);
        #pragma unroll
        for (int t = 0; t < 4; ++t) {
            bfrag8 b = wg[(t * 16 + (lane & 15)) * 32 + (g ^ swz)];
            acc[t] = __builtin_amdgcn_mfma_f32_16x16x32_bf16(a.v, b, acc[t], 0, 0, 0);
        }
    }
    // C/D: col = lane&15, row = (lane>>4)*4 + r ; scale by dinv[row] on store
    #pragma unroll
    for (int t = 0; t < 4; ++t) {
        #pragma unroll
        for (int r = 0; r < 4; ++r) {
            int row = n0 + (lane >> 4) * 4 + r;
            if (row < N_NODES) {
                float dr = dinv[row];
                hs[(size_t)row * DOUT + t * 16 + (lane & 15)] = f2bf(acc[t][r] * dr);
            }
        }
    }
}

// -------- CSR aggregate (register acc, NO LDS) + self loop + bias + LN -------
// wave per node, lane = feature. csr entries for a node are contiguous; all
// hot-loop loads are plain vector loads; accumulator lives in a VGPR.
__global__ __launch_bounds__(256) void csr_agg_ln_kernel(
    const unsigned* __restrict__ csr, const int* __restrict__ nstart,
    const int* __restrict__ nend, const unsigned short* __restrict__ hs,
    const float* __restrict__ dinv, const float* __restrict__ bias,
    const float* __restrict__ gamma, const float* __restrict__ beta,
    float* __restrict__ out) {
    int node = blockIdx.x * 4 + (threadIdx.x >> 6);
    if (node >= N_NODES) return;
    int lane = threadIdx.x & 63;
    int c = nstart[node], e2 = nend[node];
    float acc = bf2f(hs[(size_t)node * DOUT + lane]);   // self loop (pre-scaled)
    for (; c + 4 <= e2; c += 4) {
        int s0 = csr[c],     s1 = csr[c + 1];
        int s2 = csr[c + 2], s3 = csr[c + 3];
        float h0 = bf2f(hs[(size_t)s0 * DOUT + lane]);
        float h1 = bf2f(hs[(size_t)s1 * DOUT + lane]);
        float h2 = bf2f(hs[(size_t)s2 * DOUT + lane]);
        float h3 = bf2f(hs[(size_t)s3 * DOUT + lane]);
        acc += (h0 + h1) + (h2 + h3);
    }
    for (; c < e2; ++c)
        acc += bf2f(hs[(size_t)csr[c] * DOUT + lane]);
    float a = acc * dinv[node] + bias[lane];
    // LayerNorm over 64 features (one wave)
    float sum = a;
    #pragma unroll
    for (int d = 1; d < 64; d <<= 1) sum += __shfl_xor(sum, d, 64);
    float mu = sum * (1.0f / 64.0f);
    float diff = a - mu;
    float vs = diff * diff;
    #pragma unroll
    for (int d = 1; d < 64; d <<= 1) vs += __shfl_xor(vs, d, 64);
    float var = vs * (1.0f / 64.0f);
    float rinv = rsqrtf(var + LN_EPS);
    out[(size_t)node * DOUT + lane] = diff * rinv * gamma[lane] + beta[lane];
}

extern "C" void kernel_launch(void* const* d_in, const int* in_sizes, int n_in,
                              void* d_out, int out_size, void* d_ws, size_t ws_size,
                              hipStream_t stream) {
    const float* xs    = (const float*)d_in[0];
    const int*   ei    = (const int*)d_in[1];
    const float* W     = (const float*)d_in[2];
    const float* bias  = (const float*)d_in[3];
    const float* gamma = (const float*)d_in[4];
    const float* beta  = (const float*)d_in[5];
    float* out = (float*)d_out;

    char* base = (char*)d_ws;
    auto align_up = [](size_t x) { return (x + 255) & ~(size_t)255; };
    size_t o = 0;
    int* gcur   = (int*)(base + o);      o = align_up(o + (size_t)NB * 4);
    size_t zero_bytes = o;               // gcur only
    float* dinv = (float*)(base + o);    o = align_up(o + (size_t)N_NODES * 4);
    unsigned* bdata = (unsigned*)(base + o);           // becomes sorted csr
    o = align_up(o + (size_t)NB * BCAP * 4);
    unsigned short* hs = (unsigned short*)(base + o);
    o = align_up(o + (size_t)N_NODES * DOUT * 2);
    int* nstart = (int*)(base + o);      o = align_up(o + (size_t)N_NODES * 4);
    int* nend   = (int*)(base + o);      o = align_up(o + (size_t)N_NODES * 4);
    (void)ws_size; (void)in_sizes; (void)n_in; (void)out_size;

    hipMemsetAsync(d_ws, 0, zero_bytes, stream);
    partition_kernel<<<(N_EDGES + 8191) / 8192, 512, 0, stream>>>(ei, gcur, bdata);
    sort_dinv_kernel<<<NB, 512, 0, stream>>>(bdata, gcur, dinv, nstart, nend);
    gemm_kernel<<<(N_NODES + 63) / 64, 256, 0, stream>>>(xs, W, dinv, hs);
    csr_agg_ln_kernel<<<(N_NODES + 3) / 4, 256, 0, stream>>>(
        bdata, nstart, nend, hs, dinv, bias, gamma, beta, out);
}

// Round 10
// 76.389 us; speedup vs baseline: 5.5363x; 1.0732x over previous
//
#include <hip/hip_runtime.h>

#define N_NODES 50000
#define N_EDGES 800000
#define DIN 256
#define DOUT 64
#define LN_EPS 1e-5f
#define NB 782        // ceil(N_NODES/64) buckets of 64 dsts
#define BCAP 2048     // bucket capacity (mean 1024, sd ~32)

typedef __attribute__((ext_vector_type(8))) short bfrag8;
typedef __attribute__((ext_vector_type(4))) float f32x4;

__device__ inline unsigned short f2bf(float f) {
    unsigned u = __builtin_bit_cast(unsigned, f);
    u += 0x7fffu + ((u >> 16) & 1u);          // round-to-nearest-even
    return (unsigned short)(u >> 16);
}
__device__ inline float bf2f(unsigned short b) {
    unsigned u = ((unsigned)b) << 16;
    return __builtin_bit_cast(float, u);
}

// ---------------- zero gcur (replaces rocclr fillBuffer: ~40us graph node) ---
__global__ void zero_gcur_kernel(int* __restrict__ gcur) {
    int i = threadIdx.x;
    if (i < NB) gcur[i] = 0;
}

// ---------------- partition: bucket edges by dst/64 (coarse radix pass) ------
__global__ __launch_bounds__(512) void partition_kernel(
    const int* __restrict__ ei, int* __restrict__ gcur, unsigned* __restrict__ bdata) {
    __shared__ int hist[NB];
    __shared__ int hbase[NB];
    __shared__ int lcur[NB];
    const int tid = threadIdx.x;
    for (int c = tid; c < NB; c += 512) { hist[c] = 0; lcur[c] = 0; }
    __syncthreads();
    const int chunk = blockIdx.x * 8192;
    unsigned u[16];
    int bk[16];
    #pragma unroll
    for (int i = 0; i < 16; ++i) {
        int e = chunk + i * 512 + tid;
        if (e < N_EDGES) {
            int s = ei[e];
            int d = ei[N_EDGES + e];
            u[i] = (unsigned)s | ((unsigned)(d & 63) << 17);
            bk[i] = d >> 6;
            atomicAdd(&hist[bk[i]], 1);
        } else { bk[i] = -1; u[i] = 0; }
    }
    __syncthreads();
    for (int c = tid; c < NB; c += 512) {
        int n = hist[c];
        hbase[c] = n ? atomicAdd(&gcur[c], n) : 0;
    }
    __syncthreads();
    #pragma unroll
    for (int i = 0; i < 16; ++i) {
        if (bk[i] >= 0) {
            int off = hbase[bk[i]] + atomicAdd(&lcur[bk[i]], 1);
            if (off < BCAP) bdata[(size_t)bk[i] * BCAP + off] = u[i];
        }
    }
}

// ------ per-bucket counting sort by dst + dinv + per-node CSR bounds ---------
__global__ __launch_bounds__(512) void sort_dinv_kernel(
    unsigned* __restrict__ bdata, const int* __restrict__ gcur,
    float* __restrict__ dinv, int* __restrict__ nstart, int* __restrict__ nend) {
    __shared__ unsigned buf[BCAP];   // 8KB
    __shared__ int hist[64];
    __shared__ int pre[64];
    __shared__ int cur[64];
    const int tid = threadIdx.x, b = blockIdx.x;
    if (tid < 64) { hist[tid] = 0; cur[tid] = 0; }
    __syncthreads();
    int cntb = gcur[b];
    if (cntb > BCAP) cntb = BCAP;
    unsigned* bd = bdata + (size_t)b * BCAP;
    for (int i = tid; i < cntb; i += 512) {
        unsigned u = bd[i];
        buf[i] = u;
        atomicAdd(&hist[u >> 17], 1);
    }
    __syncthreads();
    if (tid < 64) {                      // wave 0: exclusive scan of hist
        int v = hist[tid], s = v;
        #pragma unroll
        for (int d = 1; d < 64; d <<= 1) {
            int t = __shfl_up(s, d, 64);
            if (tid >= d) s += t;
        }
        pre[tid] = s - v;
        int node = b * 64 + tid;
        if (node < N_NODES) {
            dinv[node] = rsqrtf((float)(v + 1));   // +1 self loop
            nstart[node] = b * BCAP + (s - v);
            nend[node]   = b * BCAP + s;
        }
    }
    __syncthreads();
    for (int i = tid; i < cntb; i += 512) {
        unsigned u = buf[i];
        int dl = (int)(u >> 17);
        int off = atomicAdd(&cur[dl], 1);
        bd[pre[dl] + off] = u & 0x1FFFF;           // store src only
    }
}

// ------- MFMA GEMM: hs[n][d] = (sum_k xs[n][k] * W[d][k]) * dinv[n], bf16 ----
__global__ __launch_bounds__(256) void gemm_kernel(const float* __restrict__ xs,
                                                   const float* __restrict__ W,
                                                   const float* __restrict__ dinv,
                                                   unsigned short* __restrict__ hs) {
    __shared__ bfrag8 wg[64 * 32];   // 32KB bf16 W
    const int tid = threadIdx.x;
    #pragma unroll
    for (int i = 0; i < 8; ++i) {
        int gi = tid + i * 256;              // 0..2047
        int d = gi >> 5, g = gi & 31;
        const float* src = W + d * 256 + g * 8;
        f32x4 f0 = *(const f32x4*)src;
        f32x4 f1 = *(const f32x4*)(src + 4);
        union { unsigned short us[8]; bfrag8 v; } p;
        p.us[0] = f2bf(f0.x); p.us[1] = f2bf(f0.y);
        p.us[2] = f2bf(f0.z); p.us[3] = f2bf(f0.w);
        p.us[4] = f2bf(f1.x); p.us[5] = f2bf(f1.y);
        p.us[6] = f2bf(f1.z); p.us[7] = f2bf(f1.w);
        wg[d * 32 + (g ^ (d & 7))] = p.v;
    }
    __syncthreads();

    const int lane = tid & 63, wv = tid >> 6;
    const int n0 = (blockIdx.x * 4 + wv) * 16;
    int arow = n0 + (lane & 15);
    if (arow >= N_NODES) arow = N_NODES - 1;          // clamp (loads only)
    const float* xrow = xs + (size_t)arow * DIN + (lane >> 4) * 8;

    f32x4 acc[4] = {{0.f, 0.f, 0.f, 0.f}, {0.f, 0.f, 0.f, 0.f},
                    {0.f, 0.f, 0.f, 0.f}, {0.f, 0.f, 0.f, 0.f}};
    const int swz = lane & 7;
    #pragma unroll
    for (int s = 0; s < 8; ++s) {
        f32x4 xa = *(const f32x4*)(xrow + s * 32);
        f32x4 xb = *(const f32x4*)(xrow + s * 32 + 4);
        union { unsigned short us[8]; bfrag8 v; } a;
        a.us[0] = f2bf(xa.x); a.us[1] = f2bf(xa.y);
        a.us[2] = f2bf(xa.z); a.us[3] = f2bf(xa.w);
        a.us[4] = f2bf(xb.x); a.us[5] = f2bf(xb.y);
        a.us[6] = f2bf(xb.z); a.us[7] = f2bf(xb.w);
        int g = s * 4 + (lane >> 4);
        #pragma unroll
        for (int t = 0; t < 4; ++t) {
            bfrag8 b = wg[(t * 16 + (lane & 15)) * 32 + (g ^ swz)];
            acc[t] = __builtin_amdgcn_mfma_f32_16x16x32_bf16(a.v, b, acc[t], 0, 0, 0);
        }
    }
    // C/D: col = lane&15, row = (lane>>4)*4 + r ; scale by dinv[row] on store
    #pragma unroll
    for (int t = 0; t < 4; ++t) {
        #pragma unroll
        for (int r = 0; r < 4; ++r) {
            int row = n0 + (lane >> 4) * 4 + r;
            if (row < N_NODES) {
                float dr = dinv[row];
                hs[(size_t)row * DOUT + t * 16 + (lane & 15)] = f2bf(acc[t][r] * dr);
            }
        }
    }
}

// -------- CSR aggregate (register acc, NO LDS) + self loop + bias + LN -------
// wave per node, lane = feature; 8-wide unrolled batches for MLP depth.
__global__ __launch_bounds__(256) void csr_agg_ln_kernel(
    const unsigned* __restrict__ csr, const int* __restrict__ nstart,
    const int* __restrict__ nend, const unsigned short* __restrict__ hs,
    const float* __restrict__ dinv, const float* __restrict__ bias,
    const float* __restrict__ gamma, const float* __restrict__ beta,
    float* __restrict__ out) {
    int node = blockIdx.x * 4 + (threadIdx.x >> 6);
    if (node >= N_NODES) return;
    int lane = threadIdx.x & 63;
    int c = nstart[node], e2 = nend[node];
    float acc = bf2f(hs[(size_t)node * DOUT + lane]);   // self loop (pre-scaled)
    for (; c + 8 <= e2; c += 8) {
        int s0 = csr[c],     s1 = csr[c + 1];
        int s2 = csr[c + 2], s3 = csr[c + 3];
        int s4 = csr[c + 4], s5 = csr[c + 5];
        int s6 = csr[c + 6], s7 = csr[c + 7];
        float h0 = bf2f(hs[(size_t)s0 * DOUT + lane]);
        float h1 = bf2f(hs[(size_t)s1 * DOUT + lane]);
        float h2 = bf2f(hs[(size_t)s2 * DOUT + lane]);
        float h3 = bf2f(hs[(size_t)s3 * DOUT + lane]);
        float h4 = bf2f(hs[(size_t)s4 * DOUT + lane]);
        float h5 = bf2f(hs[(size_t)s5 * DOUT + lane]);
        float h6 = bf2f(hs[(size_t)s6 * DOUT + lane]);
        float h7 = bf2f(hs[(size_t)s7 * DOUT + lane]);
        acc += ((h0 + h1) + (h2 + h3)) + ((h4 + h5) + (h6 + h7));
    }
    for (; c + 4 <= e2; c += 4) {
        int s0 = csr[c],     s1 = csr[c + 1];
        int s2 = csr[c + 2], s3 = csr[c + 3];
        float h0 = bf2f(hs[(size_t)s0 * DOUT + lane]);
        float h1 = bf2f(hs[(size_t)s1 * DOUT + lane]);
        float h2 = bf2f(hs[(size_t)s2 * DOUT + lane]);
        float h3 = bf2f(hs[(size_t)s3 * DOUT + lane]);
        acc += (h0 + h1) + (h2 + h3);
    }
    for (; c < e2; ++c)
        acc += bf2f(hs[(size_t)csr[c] * DOUT + lane]);
    float a = acc * dinv[node] + bias[lane];
    // LayerNorm over 64 features (one wave)
    float sum = a;
    #pragma unroll
    for (int d = 1; d < 64; d <<= 1) sum += __shfl_xor(sum, d, 64);
    float mu = sum * (1.0f / 64.0f);
    float diff = a - mu;
    float vs = diff * diff;
    #pragma unroll
    for (int d = 1; d < 64; d <<= 1) vs += __shfl_xor(vs, d, 64);
    float var = vs * (1.0f / 64.0f);
    float rinv = rsqrtf(var + LN_EPS);
    out[(size_t)node * DOUT + lane] = diff * rinv * gamma[lane] + beta[lane];
}

extern "C" void kernel_launch(void* const* d_in, const int* in_sizes, int n_in,
                              void* d_out, int out_size, void* d_ws, size_t ws_size,
                              hipStream_t stream) {
    const float* xs    = (const float*)d_in[0];
    const int*   ei    = (const int*)d_in[1];
    const float* W     = (const float*)d_in[2];
    const float* bias  = (const float*)d_in[3];
    const float* gamma = (const float*)d_in[4];
    const float* beta  = (const float*)d_in[5];
    float* out = (float*)d_out;

    char* base = (char*)d_ws;
    auto align_up = [](size_t x) { return (x + 255) & ~(size_t)255; };
    size_t o = 0;
    int* gcur   = (int*)(base + o);      o = align_up(o + (size_t)NB * 4);
    float* dinv = (float*)(base + o);    o = align_up(o + (size_t)N_NODES * 4);
    unsigned* bdata = (unsigned*)(base + o);           // becomes sorted csr
    o = align_up(o + (size_t)NB * BCAP * 4);
    unsigned short* hs = (unsigned short*)(base + o);
    o = align_up(o + (size_t)N_NODES * DOUT * 2);
    int* nstart = (int*)(base + o);      o = align_up(o + (size_t)N_NODES * 4);
    int* nend   = (int*)(base + o);      o = align_up(o + (size_t)N_NODES * 4);
    (void)ws_size; (void)in_sizes; (void)n_in; (void)out_size;

    zero_gcur_kernel<<<1, 1024, 0, stream>>>(gcur);
    partition_kernel<<<(N_EDGES + 8191) / 8192, 512, 0, stream>>>(ei, gcur, bdata);
    sort_dinv_kernel<<<NB, 512, 0, stream>>>(bdata, gcur, dinv, nstart, nend);
    gemm_kernel<<<(N_NODES + 63) / 64, 256, 0, stream>>>(xs, W, dinv, hs);
    csr_agg_ln_kernel<<<(N_NODES + 3) / 4, 256, 0, stream>>>(
        bdata, nstart, nend, hs, dinv, bias, gamma, beta, out);
}

// Round 11
// 64.643 us; speedup vs baseline: 6.5422x; 1.1817x over previous
//
#include <hip/hip_runtime.h>

#define N_NODES 50000
#define N_EDGES 800000
#define DIN 256
#define DOUT 64
#define LN_EPS 1e-5f
#define NB 782        // ceil(N_NODES/64) buckets of 64 dsts
#define BCAP 2048     // bucket capacity (mean 1024, sd ~32)

typedef __attribute__((ext_vector_type(8))) short bfrag8;
typedef __attribute__((ext_vector_type(4))) float f32x4;

__device__ inline unsigned short f2bf(float f) {
    unsigned u = __builtin_bit_cast(unsigned, f);
    u += 0x7fffu + ((u >> 16) & 1u);          // round-to-nearest-even
    return (unsigned short)(u >> 16);
}
__device__ inline float bf2f(unsigned short b) {
    unsigned u = ((unsigned)b) << 16;
    return __builtin_bit_cast(float, u);
}

// ---------------- zero gcur ----------------
__global__ void zero_gcur_kernel(int* __restrict__ gcur) {
    int i = threadIdx.x;
    if (i < NB) gcur[i] = 0;
}

// ---------------- partition: bucket edges by dst/64 (coarse radix pass) ------
__global__ __launch_bounds__(512) void partition_kernel(
    const int* __restrict__ ei, int* __restrict__ gcur, unsigned* __restrict__ bdata) {
    __shared__ int hist[NB];
    __shared__ int hbase[NB];
    __shared__ int lcur[NB];
    const int tid = threadIdx.x;
    for (int c = tid; c < NB; c += 512) { hist[c] = 0; lcur[c] = 0; }
    __syncthreads();
    const int chunk = blockIdx.x * 8192;
    unsigned u[16];
    int bk[16];
    #pragma unroll
    for (int i = 0; i < 16; ++i) {
        int e = chunk + i * 512 + tid;
        if (e < N_EDGES) {
            int s = ei[e];
            int d = ei[N_EDGES + e];
            u[i] = (unsigned)s | ((unsigned)(d & 63) << 17);
            bk[i] = d >> 6;
            atomicAdd(&hist[bk[i]], 1);
        } else { bk[i] = -1; u[i] = 0; }
    }
    __syncthreads();
    for (int c = tid; c < NB; c += 512) {
        int n = hist[c];
        hbase[c] = n ? atomicAdd(&gcur[c], n) : 0;
    }
    __syncthreads();
    #pragma unroll
    for (int i = 0; i < 16; ++i) {
        if (bk[i] >= 0) {
            int off = hbase[bk[i]] + atomicAdd(&lcur[bk[i]], 1);
            if (off < BCAP) bdata[(size_t)bk[i] * BCAP + off] = u[i];
        }
    }
}

// ------ per-bucket counting sort by dst + dinv + per-node CSR bounds ---------
__global__ __launch_bounds__(512) void sort_dinv_kernel(
    unsigned* __restrict__ bdata, const int* __restrict__ gcur,
    float* __restrict__ dinv, int* __restrict__ nstart, int* __restrict__ nend) {
    __shared__ unsigned buf[BCAP];   // 8KB
    __shared__ int hist[64];
    __shared__ int pre[64];
    __shared__ int cur[64];
    const int tid = threadIdx.x, b = blockIdx.x;
    if (tid < 64) { hist[tid] = 0; cur[tid] = 0; }
    __syncthreads();
    int cntb = gcur[b];
    if (cntb > BCAP) cntb = BCAP;
    unsigned* bd = bdata + (size_t)b * BCAP;
    for (int i = tid; i < cntb; i += 512) {
        unsigned u = bd[i];
        buf[i] = u;
        atomicAdd(&hist[u >> 17], 1);
    }
    __syncthreads();
    if (tid < 64) {                      // wave 0: exclusive scan of hist
        int v = hist[tid], s = v;
        #pragma unroll
        for (int d = 1; d < 64; d <<= 1) {
            int t = __shfl_up(s, d, 64);
            if (tid >= d) s += t;
        }
        pre[tid] = s - v;
        int node = b * 64 + tid;
        if (node < N_NODES) {
            dinv[node] = rsqrtf((float)(v + 1));   // +1 self loop
            nstart[node] = b * BCAP + (s - v);
            nend[node]   = b * BCAP + s;
        }
    }
    __syncthreads();
    for (int i = tid; i < cntb; i += 512) {
        unsigned u = buf[i];
        int dl = (int)(u >> 17);
        int off = atomicAdd(&cur[dl], 1);
        bd[pre[dl] + off] = u & 0x1FFFF;           // store src only
    }
}

// ------- MFMA GEMM: hs[n][d] = (sum_k xs[n][k] * W[d][k]) * dinv[n], bf16 ----
__global__ __launch_bounds__(256) void gemm_kernel(const float* __restrict__ xs,
                                                   const float* __restrict__ W,
                                                   const float* __restrict__ dinv,
                                                   unsigned short* __restrict__ hs) {
    __shared__ bfrag8 wg[64 * 32];   // 32KB bf16 W
    const int tid = threadIdx.x;
    #pragma unroll
    for (int i = 0; i < 8; ++i) {
        int gi = tid + i * 256;              // 0..2047
        int d = gi >> 5, g = gi & 31;
        const float* src = W + d * 256 + g * 8;
        f32x4 f0 = *(const f32x4*)src;
        f32x4 f1 = *(const f32x4*)(src + 4);
        union { unsigned short us[8]; bfrag8 v; } p;
        p.us[0] = f2bf(f0.x); p.us[1] = f2bf(f0.y);
        p.us[2] = f2bf(f0.z); p.us[3] = f2bf(f0.w);
        p.us[4] = f2bf(f1.x); p.us[5] = f2bf(f1.y);
        p.us[6] = f2bf(f1.z); p.us[7] = f2bf(f1.w);
        wg[d * 32 + (g ^ (d & 7))] = p.v;
    }
    __syncthreads();

    const int lane = tid & 63, wv = tid >> 6;
    const int n0 = (blockIdx.x * 4 + wv) * 16;
    int arow = n0 + (lane & 15);
    if (arow >= N_NODES) arow = N_NODES - 1;          // clamp (loads only)
    const float* xrow = xs + (size_t)arow * DIN + (lane >> 4) * 8;

    f32x4 acc[4] = {{0.f, 0.f, 0.f, 0.f}, {0.f, 0.f, 0.f, 0.f},
                    {0.f, 0.f, 0.f, 0.f}, {0.f, 0.f, 0.f, 0.f}};
    const int swz = lane & 7;
    #pragma unroll
    for (int s = 0; s < 8; ++s) {
        f32x4 xa = *(const f32x4*)(xrow + s * 32);
        f32x4 xb = *(const f32x4*)(xrow + s * 32 + 4);
        union { unsigned short us[8]; bfrag8 v; } a;
        a.us[0] = f2bf(xa.x); a.us[1] = f2bf(xa.y);
        a.us[2] = f2bf(xa.z); a.us[3] = f2bf(xa.w);
        a.us[4] = f2bf(xb.x); a.us[5] = f2bf(xb.y);
        a.us[6] = f2bf(xb.z); a.us[7] = f2bf(xb.w);
        int g = s * 4 + (lane >> 4);
        #pragma unroll
        for (int t = 0; t < 4; ++t) {
            bfrag8 b = wg[(t * 16 + (lane & 15)) * 32 + (g ^ swz)];
            acc[t] = __builtin_amdgcn_mfma_f32_16x16x32_bf16(a.v, b, acc[t], 0, 0, 0);
        }
    }
    // C/D: col = lane&15, row = (lane>>4)*4 + r ; scale by dinv[row] on store
    #pragma unroll
    for (int t = 0; t < 4; ++t) {
        #pragma unroll
        for (int r = 0; r < 4; ++r) {
            int row = n0 + (lane >> 4) * 4 + r;
            if (row < N_NODES) {
                float dr = dinv[row];
                hs[(size_t)row * DOUT + t * 16 + (lane & 15)] = f2bf(acc[t][r] * dr);
            }
        }
    }
}

// -------- CSR aggregate: 4 nodes/wave, 16 lanes/node, uint2 (4 bf16)/lane ----
// Each hs-row load instruction fetches 4 independent edge rows (4x128B) ->
// 4-row MLP per instruction, x8 unroll = 32 rows in flight. No branches, no
// LDS atomics in hot loop: clamped unconditional loads + cndmask masking.
__global__ __launch_bounds__(256) void csr_agg_ln_kernel(
    const unsigned* __restrict__ csr, const int* __restrict__ nstart,
    const int* __restrict__ nend, const unsigned short* __restrict__ hs,
    const float* __restrict__ dinv, const float* __restrict__ bias,
    const float* __restrict__ gamma, const float* __restrict__ beta,
    float* __restrict__ out) {
    const int tid = threadIdx.x, lane = tid & 63, wv = tid >> 6;
    const int q = lane >> 4;          // which of the wave's 4 nodes
    const int fl = lane & 15;         // feature group (4 feats) within node
    const int node = (blockIdx.x * 4 + wv) * 4 + q;   // 50000 % 16 == 0
    if (node >= N_NODES) return;
    const int c0 = nstart[node];
    const int deg = nend[node] - c0;
    const int cmax = deg > 0 ? deg - 1 : 0;

    // self loop (hs pre-scaled by dinv[src])
    uint2 sv = *(const uint2*)(hs + (size_t)node * DOUT + fl * 4);
    float a0 = bf2f((unsigned short)(sv.x & 0xFFFFu));
    float a1 = bf2f((unsigned short)(sv.x >> 16));
    float a2 = bf2f((unsigned short)(sv.y & 0xFFFFu));
    float a3 = bf2f((unsigned short)(sv.y >> 16));

    int maxd = deg;
    maxd = max(maxd, __shfl_xor(maxd, 16, 64));
    maxd = max(maxd, __shfl_xor(maxd, 32, 64));

    for (int j = 0; j < maxd; j += 8) {
        unsigned uu[8];
        #pragma unroll
        for (int k = 0; k < 8; ++k) {
            int jc = j + k; jc = jc < cmax ? jc : cmax;   // clamp, unconditional
            uu[k] = csr[c0 + jc];
        }
        uint2 hv[8];
        #pragma unroll
        for (int k = 0; k < 8; ++k) {
            unsigned src = uu[k];
            if (src > (unsigned)(N_NODES - 1)) src = N_NODES - 1;  // v_min_u32
            hv[k] = *(const uint2*)(hs + (size_t)src * DOUT + fl * 4);
        }
        #pragma unroll
        for (int k = 0; k < 8; ++k) {
            bool valid = (j + k) < deg;
            unsigned x = valid ? hv[k].x : 0u;   // cndmask, no branch
            unsigned y = valid ? hv[k].y : 0u;
            a0 += bf2f((unsigned short)(x & 0xFFFFu));
            a1 += bf2f((unsigned short)(x >> 16));
            a2 += bf2f((unsigned short)(y & 0xFFFFu));
            a3 += bf2f((unsigned short)(y >> 16));
        }
    }
    float di = dinv[node];
    float4 b4  = ((const float4*)bias)[fl];
    float4 g4  = ((const float4*)gamma)[fl];
    float4 be4 = ((const float4*)beta)[fl];
    a0 = a0 * di + b4.x;
    a1 = a1 * di + b4.y;
    a2 = a2 * di + b4.z;
    a3 = a3 * di + b4.w;
    // LayerNorm over 64 features = 16-lane group x 4 per lane
    float sum = (a0 + a1) + (a2 + a3);
    #pragma unroll
    for (int d = 1; d < 16; d <<= 1) sum += __shfl_xor(sum, d, 64);
    float mu = sum * (1.0f / 64.0f);
    float d0 = a0 - mu, d1 = a1 - mu, d2 = a2 - mu, d3 = a3 - mu;
    float vs = (d0 * d0 + d1 * d1) + (d2 * d2 + d3 * d3);
    #pragma unroll
    for (int d = 1; d < 16; d <<= 1) vs += __shfl_xor(vs, d, 64);
    float var = vs * (1.0f / 64.0f);
    float rinv = rsqrtf(var + LN_EPS);
    float4 ov;
    ov.x = d0 * rinv * g4.x + be4.x;
    ov.y = d1 * rinv * g4.y + be4.y;
    ov.z = d2 * rinv * g4.z + be4.z;
    ov.w = d3 * rinv * g4.w + be4.w;
    *(float4*)(out + (size_t)node * DOUT + fl * 4) = ov;
}

extern "C" void kernel_launch(void* const* d_in, const int* in_sizes, int n_in,
                              void* d_out, int out_size, void* d_ws, size_t ws_size,
                              hipStream_t stream) {
    const float* xs    = (const float*)d_in[0];
    const int*   ei    = (const int*)d_in[1];
    const float* W     = (const float*)d_in[2];
    const float* bias  = (const float*)d_in[3];
    const float* gamma = (const float*)d_in[4];
    const float* beta  = (const float*)d_in[5];
    float* out = (float*)d_out;

    char* base = (char*)d_ws;
    auto align_up = [](size_t x) { return (x + 255) & ~(size_t)255; };
    size_t o = 0;
    int* gcur   = (int*)(base + o);      o = align_up(o + (size_t)NB * 4);
    float* dinv = (float*)(base + o);    o = align_up(o + (size_t)N_NODES * 4);
    unsigned* bdata = (unsigned*)(base + o);           // becomes sorted csr
    o = align_up(o + (size_t)NB * BCAP * 4);
    unsigned short* hs = (unsigned short*)(base + o);
    o = align_up(o + (size_t)N_NODES * DOUT * 2);
    int* nstart = (int*)(base + o);      o = align_up(o + (size_t)N_NODES * 4);
    int* nend   = (int*)(base + o);      o = align_up(o + (size_t)N_NODES * 4);
    (void)ws_size; (void)in_sizes; (void)n_in; (void)out_size;

    zero_gcur_kernel<<<1, 1024, 0, stream>>>(gcur);
    partition_kernel<<<(N_EDGES + 8191) / 8192, 512, 0, stream>>>(ei, gcur, bdata);
    sort_dinv_kernel<<<NB, 512, 0, stream>>>(bdata, gcur, dinv, nstart, nend);
    gemm_kernel<<<(N_NODES + 63) / 64, 256, 0, stream>>>(xs, W, dinv, hs);
    csr_agg_ln_kernel<<<(N_NODES + 15) / 16, 256, 0, stream>>>(
        bdata, nstart, nend, hs, dinv, bias, gamma, beta, out);
}

// Round 12
// 61.680 us; speedup vs baseline: 6.8565x; 1.0480x over previous
//
#include <hip/hip_runtime.h>

#define N_NODES 50000
#define N_EDGES 800000
#define DIN 256
#define DOUT 64
#define LN_EPS 1e-5f
#define NB 782        // ceil(N_NODES/64) buckets of 64 dsts
#define BCAP 2048     // bucket capacity (mean 1024, sd ~32)

typedef __attribute__((ext_vector_type(8))) short bfrag8;
typedef __attribute__((ext_vector_type(4))) float f32x4;

__device__ inline unsigned short f2bf(float f) {
    unsigned u = __builtin_bit_cast(unsigned, f);
    u += 0x7fffu + ((u >> 16) & 1u);          // round-to-nearest-even
    return (unsigned short)(u >> 16);
}
__device__ inline float bf2f(unsigned short b) {
    unsigned u = ((unsigned)b) << 16;
    return __builtin_bit_cast(float, u);
}

// ---------------- zero gcur ----------------
__global__ void zero_gcur_kernel(int* __restrict__ gcur) {
    int i = threadIdx.x;
    if (i < NB) gcur[i] = 0;
}

// ---------------- partition: bucket edges by dst/64 (coarse radix pass) ------
// Rank trick: the hist atomicAdd RETURNS each edge's local rank -> no second
// lcur atomic pass (halves LDS atomics).
__global__ __launch_bounds__(512) void partition_kernel(
    const int* __restrict__ ei, int* __restrict__ gcur, unsigned* __restrict__ bdata) {
    __shared__ int hist[NB];
    __shared__ int hbase[NB];
    const int tid = threadIdx.x;
    for (int c = tid; c < NB; c += 512) hist[c] = 0;
    __syncthreads();
    const int chunk = blockIdx.x * 8192;
    unsigned u[16];
    int bk[16];
    int rk[16];
    #pragma unroll
    for (int i = 0; i < 16; ++i) {
        int e = chunk + i * 512 + tid;
        if (e < N_EDGES) {
            int s = ei[e];
            int d = ei[N_EDGES + e];
            u[i] = (unsigned)s | ((unsigned)(d & 63) << 17);
            bk[i] = d >> 6;
            rk[i] = atomicAdd(&hist[bk[i]], 1);
        } else { bk[i] = -1; u[i] = 0; rk[i] = 0; }
    }
    __syncthreads();
    for (int c = tid; c < NB; c += 512) {
        int n = hist[c];
        hbase[c] = n ? atomicAdd(&gcur[c], n) : 0;
    }
    __syncthreads();
    #pragma unroll
    for (int i = 0; i < 16; ++i) {
        if (bk[i] >= 0) {
            int off = hbase[bk[i]] + rk[i];
            if (off < BCAP) bdata[(size_t)bk[i] * BCAP + off] = u[i];
        }
    }
}

// ------ per-bucket counting sort by dst + dinv + per-node CSR bounds ---------
// Values stay in registers (<=4/thread, fully unrolled); rank from the hist
// atomicAdd; scatter into LDS by rank; write bucket back CONTIGUOUSLY.
__global__ __launch_bounds__(512) void sort_dinv_kernel(
    unsigned* __restrict__ bdata, const int* __restrict__ gcur,
    float* __restrict__ dinv, int* __restrict__ nstart, int* __restrict__ nend) {
    __shared__ unsigned buf[BCAP];   // 8KB
    __shared__ int hist[64];
    __shared__ int pre[64];
    const int tid = threadIdx.x, b = blockIdx.x;
    if (tid < 64) hist[tid] = 0;
    __syncthreads();
    int cntb = gcur[b];
    if (cntb > BCAP) cntb = BCAP;
    unsigned* bd = bdata + (size_t)b * BCAP;
    unsigned v[4];
    int rk[4];
    #pragma unroll
    for (int j = 0; j < 4; ++j) {
        int i = tid + j * 512;
        if (i < cntb) {
            v[j] = bd[i];
            rk[j] = atomicAdd(&hist[v[j] >> 17], 1);
        } else { v[j] = 0; rk[j] = -1; }
    }
    __syncthreads();
    if (tid < 64) {                      // wave 0: exclusive scan of hist
        int n = hist[tid], s = n;
        #pragma unroll
        for (int d = 1; d < 64; d <<= 1) {
            int t = __shfl_up(s, d, 64);
            if (tid >= d) s += t;
        }
        pre[tid] = s - n;
        int node = b * 64 + tid;
        if (node < N_NODES) {
            dinv[node] = rsqrtf((float)(n + 1));   // +1 self loop
            nstart[node] = b * BCAP + (s - n);
            nend[node]   = b * BCAP + s;
        }
    }
    __syncthreads();
    #pragma unroll
    for (int j = 0; j < 4; ++j) {
        if (rk[j] >= 0)
            buf[pre[v[j] >> 17] + rk[j]] = v[j] & 0x1FFFF;   // src only
    }
    __syncthreads();
    #pragma unroll
    for (int j = 0; j < 4; ++j) {
        int i = tid + j * 512;
        if (i < cntb) bd[i] = buf[i];    // coalesced writeback
    }
}

// ------- MFMA GEMM: hs[n][d] = (sum_k xs[n][k] * W[d][k]) * dinv[n], bf16 ----
// 512 thr = 8 waves, 128 rows/block: halves W stagings vs 256-thr blocks.
__global__ __launch_bounds__(512) void gemm_kernel(const float* __restrict__ xs,
                                                   const float* __restrict__ W,
                                                   const float* __restrict__ dinv,
                                                   unsigned short* __restrict__ hs) {
    __shared__ bfrag8 wg[64 * 32];   // 32KB bf16 W
    const int tid = threadIdx.x;
    #pragma unroll
    for (int i = 0; i < 4; ++i) {
        int gi = tid + i * 512;              // 0..2047
        int d = gi >> 5, g = gi & 31;
        const float* src = W + d * 256 + g * 8;
        f32x4 f0 = *(const f32x4*)src;
        f32x4 f1 = *(const f32x4*)(src + 4);
        union { unsigned short us[8]; bfrag8 v; } p;
        p.us[0] = f2bf(f0.x); p.us[1] = f2bf(f0.y);
        p.us[2] = f2bf(f0.z); p.us[3] = f2bf(f0.w);
        p.us[4] = f2bf(f1.x); p.us[5] = f2bf(f1.y);
        p.us[6] = f2bf(f1.z); p.us[7] = f2bf(f1.w);
        wg[d * 32 + (g ^ (d & 7))] = p.v;
    }
    __syncthreads();

    const int lane = tid & 63, wv = tid >> 6;
    const int n0 = (blockIdx.x * 8 + wv) * 16;
    int arow = n0 + (lane & 15);
    if (arow >= N_NODES) arow = N_NODES - 1;          // clamp (loads only)
    const float* xrow = xs + (size_t)arow * DIN + (lane >> 4) * 8;

    f32x4 acc[4] = {{0.f, 0.f, 0.f, 0.f}, {0.f, 0.f, 0.f, 0.f},
                    {0.f, 0.f, 0.f, 0.f}, {0.f, 0.f, 0.f, 0.f}};
    const int swz = lane & 7;
    #pragma unroll
    for (int s = 0; s < 8; ++s) {
        f32x4 xa = *(const f32x4*)(xrow + s * 32);
        f32x4 xb = *(const f32x4*)(xrow + s * 32 + 4);
        union { unsigned short us[8]; bfrag8 v; } a;
        a.us[0] = f2bf(xa.x); a.us[1] = f2bf(xa.y);
        a.us[2] = f2bf(xa.z); a.us[3] = f2bf(xa.w);
        a.us[4] = f2bf(xb.x); a.us[5] = f2bf(xb.y);
        a.us[6] = f2bf(xb.z); a.us[7] = f2bf(xb.w);
        int g = s * 4 + (lane >> 4);
        #pragma unroll
        for (int t = 0; t < 4; ++t) {
            bfrag8 b = wg[(t * 16 + (lane & 15)) * 32 + (g ^ swz)];
            acc[t] = __builtin_amdgcn_mfma_f32_16x16x32_bf16(a.v, b, acc[t], 0, 0, 0);
        }
    }
    // C/D: col = lane&15, row = (lane>>4)*4 + r ; scale by dinv[row] on store
    #pragma unroll
    for (int t = 0; t < 4; ++t) {
        #pragma unroll
        for (int r = 0; r < 4; ++r) {
            int row = n0 + (lane >> 4) * 4 + r;
            if (row < N_NODES) {
                float dr = dinv[row];
                hs[(size_t)row * DOUT + t * 16 + (lane & 15)] = f2bf(acc[t][r] * dr);
            }
        }
    }
}

// -------- CSR aggregate: 4 nodes/wave, 16 lanes/node, uint2 (4 bf16)/lane ----
__global__ __launch_bounds__(256) void csr_agg_ln_kernel(
    const unsigned* __restrict__ csr, const int* __restrict__ nstart,
    const int* __restrict__ nend, const unsigned short* __restrict__ hs,
    const float* __restrict__ dinv, const float* __restrict__ bias,
    const float* __restrict__ gamma, const float* __restrict__ beta,
    float* __restrict__ out) {
    const int tid = threadIdx.x, lane = tid & 63, wv = tid >> 6;
    const int q = lane >> 4;          // which of the wave's 4 nodes
    const int fl = lane & 15;         // feature group (4 feats) within node
    const int node = (blockIdx.x * 4 + wv) * 4 + q;
    if (node >= N_NODES) return;
    const int c0 = nstart[node];
    const int deg = nend[node] - c0;
    const int cmax = deg > 0 ? deg - 1 : 0;

    // self loop (hs pre-scaled by dinv[src])
    uint2 sv = *(const uint2*)(hs + (size_t)node * DOUT + fl * 4);
    float a0 = bf2f((unsigned short)(sv.x & 0xFFFFu));
    float a1 = bf2f((unsigned short)(sv.x >> 16));
    float a2 = bf2f((unsigned short)(sv.y & 0xFFFFu));
    float a3 = bf2f((unsigned short)(sv.y >> 16));

    int maxd = deg;
    maxd = max(maxd, __shfl_xor(maxd, 16, 64));
    maxd = max(maxd, __shfl_xor(maxd, 32, 64));

    for (int j = 0; j < maxd; j += 8) {
        unsigned uu[8];
        #pragma unroll
        for (int k = 0; k < 8; ++k) {
            int jc = j + k; jc = jc < cmax ? jc : cmax;   // clamp, unconditional
            uu[k] = csr[c0 + jc];
        }
        uint2 hv[8];
        #pragma unroll
        for (int k = 0; k < 8; ++k) {
            unsigned src = uu[k];
            if (src > (unsigned)(N_NODES - 1)) src = N_NODES - 1;
            hv[k] = *(const uint2*)(hs + (size_t)src * DOUT + fl * 4);
        }
        #pragma unroll
        for (int k = 0; k < 8; ++k) {
            bool valid = (j + k) < deg;
            unsigned x = valid ? hv[k].x : 0u;   // cndmask, no branch
            unsigned y = valid ? hv[k].y : 0u;
            a0 += bf2f((unsigned short)(x & 0xFFFFu));
            a1 += bf2f((unsigned short)(x >> 16));
            a2 += bf2f((unsigned short)(y & 0xFFFFu));
            a3 += bf2f((unsigned short)(y >> 16));
        }
    }
    float di = dinv[node];
    float4 b4  = ((const float4*)bias)[fl];
    float4 g4  = ((const float4*)gamma)[fl];
    float4 be4 = ((const float4*)beta)[fl];
    a0 = a0 * di + b4.x;
    a1 = a1 * di + b4.y;
    a2 = a2 * di + b4.z;
    a3 = a3 * di + b4.w;
    // LayerNorm over 64 features = 16-lane group x 4 per lane
    float sum = (a0 + a1) + (a2 + a3);
    #pragma unroll
    for (int d = 1; d < 16; d <<= 1) sum += __shfl_xor(sum, d, 64);
    float mu = sum * (1.0f / 64.0f);
    float d0 = a0 - mu, d1 = a1 - mu, d2 = a2 - mu, d3 = a3 - mu;
    float vs = (d0 * d0 + d1 * d1) + (d2 * d2 + d3 * d3);
    #pragma unroll
    for (int d = 1; d < 16; d <<= 1) vs += __shfl_xor(vs, d, 64);
    float var = vs * (1.0f / 64.0f);
    float rinv = rsqrtf(var + LN_EPS);
    float4 ov;
    ov.x = d0 * rinv * g4.x + be4.x;
    ov.y = d1 * rinv * g4.y + be4.y;
    ov.z = d2 * rinv * g4.z + be4.z;
    ov.w = d3 * rinv * g4.w + be4.w;
    *(float4*)(out + (size_t)node * DOUT + fl * 4) = ov;
}

extern "C" void kernel_launch(void* const* d_in, const int* in_sizes, int n_in,
                              void* d_out, int out_size, void* d_ws, size_t ws_size,
                              hipStream_t stream) {
    const float* xs    = (const float*)d_in[0];
    const int*   ei    = (const int*)d_in[1];
    const float* W     = (const float*)d_in[2];
    const float* bias  = (const float*)d_in[3];
    const float* gamma = (const float*)d_in[4];
    const float* beta  = (const float*)d_in[5];
    float* out = (float*)d_out;

    char* base = (char*)d_ws;
    auto align_up = [](size_t x) { return (x + 255) & ~(size_t)255; };
    size_t o = 0;
    int* gcur   = (int*)(base + o);      o = align_up(o + (size_t)NB * 4);
    float* dinv = (float*)(base + o);    o = align_up(o + (size_t)N_NODES * 4);
    unsigned* bdata = (unsigned*)(base + o);           // becomes sorted csr
    o = align_up(o + (size_t)NB * BCAP * 4);
    unsigned short* hs = (unsigned short*)(base + o);
    o = align_up(o + (size_t)N_NODES * DOUT * 2);
    int* nstart = (int*)(base + o);      o = align_up(o + (size_t)N_NODES * 4);
    int* nend   = (int*)(base + o);      o = align_up(o + (size_t)N_NODES * 4);
    (void)ws_size; (void)in_sizes; (void)n_in; (void)out_size;

    zero_gcur_kernel<<<1, 1024, 0, stream>>>(gcur);
    partition_kernel<<<(N_EDGES + 8191) / 8192, 512, 0, stream>>>(ei, gcur, bdata);
    sort_dinv_kernel<<<NB, 512, 0, stream>>>(bdata, gcur, dinv, nstart, nend);
    gemm_kernel<<<(N_NODES + 127) / 128, 512, 0, stream>>>(xs, W, dinv, hs);
    csr_agg_ln_kernel<<<(N_NODES + 15) / 16, 256, 0, stream>>>(
        bdata, nstart, nend, hs, dinv, bias, gamma, beta, out);
}